// Round 1
// baseline (518.924 us; speedup 1.0000x reference)
//
#include <hip/hip_runtime.h>

#define SQ 2048
#define BB 2
#define EE 1024
#define HH 16
#define DD 64
#define MM (SQ*BB)          // 4096 composite rows (s*B + b)
#define NSLICE 4
#define KSLICE (SQ/NSLICE)  // 512 k per attn_main wg
#define KT_IN (KSLICE/128)  // 4 kt tiles of 128
#define LOG2E 1.44269504f

typedef _Float16 f16;
typedef _Float16 half8 __attribute__((ext_vector_type(8)));
typedef _Float16 half4 __attribute__((ext_vector_type(4)));
typedef float f32x4 __attribute__((ext_vector_type(4)));

static __device__ __forceinline__ f32x4 mfma16(half8 a, half8 b, f32x4 c) {
    return __builtin_amdgcn_mfma_f32_16x16x32_f16(a, b, c, 0, 0, 0);
}

// async global->LDS, 16B per lane (GEMM staging only)
static __device__ __forceinline__ void gload16(const f16* g, f16* l) {
    __builtin_amdgcn_global_load_lds(
        (const __attribute__((address_space(1))) unsigned int*)g,
        (__attribute__((address_space(3))) unsigned int*)l, 16, 0, 0);
}

// ---------------- fused elementwise converts ----------------
__global__ void k_elem(const float* __restrict__ q_w, const float* __restrict__ k_w,
                       const float* __restrict__ v_w, const float* __restrict__ query,
                       const float* __restrict__ key, const float* __restrict__ value,
                       const float* __restrict__ owm, const float* __restrict__ owl,
                       const float* __restrict__ eps,
                       f16* qw16, f16* kw16, f16* vw16,
                       f16* xq16, f16* xk16, f16* xv16, f16* ow16)
{
    int y = blockIdx.y;
    size_t i = ((size_t)blockIdx.x * 256 + threadIdx.x) * 4;
    if (y < 3) {
        if (i >= (size_t)EE*EE) return;
        const float* s = (y==0) ? q_w : (y==1) ? k_w : v_w;
        f16* d = (y==0) ? qw16 : (y==1) ? kw16 : vw16;
        float4 v = *(const float4*)&s[i];
        half4 o = {(f16)v.x, (f16)v.y, (f16)v.z, (f16)v.w};
        *(half4*)&d[i] = o;
    } else if (y < 6) {
        const float* s = (y==3) ? query : (y==4) ? key : value;
        f16* d = (y==3) ? xq16 : (y==4) ? xk16 : xv16;
        float4 v = *(const float4*)&s[i];
        half4 o = {(f16)v.x, (f16)v.y, (f16)v.z, (f16)v.w};
        *(half4*)&d[i] = o;
    } else {
        if (i >= (size_t)EE*EE) return;
        float4 m = *(const float4*)&owm[i];
        float4 l = *(const float4*)&owl[i];
        float4 e = *(const float4*)&eps[i];
        half4 o = {(f16)(m.x + e.x * __expf(l.x)), (f16)(m.y + e.y * __expf(l.y)),
                   (f16)(m.z + e.z * __expf(l.z)), (f16)(m.w + e.w * __expf(l.w))};
        *(half4*)&ow16[i] = o;
    }
}

// ---------------- GEMM body: C[M,N] = (A[M,K] @ W[N,K]^T + bias) * scale ----------------
// 128x64 tile, BK=32. mode: 0 = f16 row-major, 1 = f16 V-transposed [b][d][s], 2 = f32.
__device__ __forceinline__ void gemm_body(
    const f16* __restrict__ A, const f16* __restrict__ W,
    const float* __restrict__ bias, float scale, void* __restrict__ out, int mode)
{
    __shared__ f16 As[128*32];
    __shared__ f16 Bs[64*32];
    int t = threadIdx.x, lane = t & 63, w = t >> 6;
    int quad = lane >> 4, m16 = lane & 15;
    int wm = w >> 1, wn = w & 1;
    int gm0 = blockIdx.x * 128, gn0 = blockIdx.y * 64;
    int arow = lane >> 2, apch = lane & 3;
    f32x4 acc[4][2] = {};
    for (int kt = 0; kt < EE; kt += 32) {
        #pragma unroll
        for (int j = 0; j < 2; ++j) {
            int row = w*32 + j*16 + arow;
            int lch = apch ^ (row & 3);
            gload16(&A[(size_t)(gm0+row)*EE + kt + lch*8], &As[row*32 + apch*8]);
        }
        {
            int row = w*16 + arow;
            int lch = apch ^ (row & 3);
            gload16(&W[(size_t)(gn0+row)*EE + kt + lch*8], &Bs[row*32 + apch*8]);
        }
        __syncthreads();
        int cs = (quad ^ (m16 & 3)) * 8;
        half8 af[4], bf[2];
        #pragma unroll
        for (int i = 0; i < 4; ++i) af[i] = *(half8*)&As[(wm*64 + i*16 + m16)*32 + cs];
        #pragma unroll
        for (int j = 0; j < 2; ++j) bf[j] = *(half8*)&Bs[(wn*32 + j*16 + m16)*32 + cs];
        #pragma unroll
        for (int i = 0; i < 4; ++i)
            #pragma unroll
            for (int j = 0; j < 2; ++j)
                acc[i][j] = mfma16(af[i], bf[j], acc[i][j]);
        __syncthreads();
    }
    #pragma unroll
    for (int j = 0; j < 2; ++j) {
        int col = gn0 + wn*32 + j*16 + m16;
        float bb = bias ? bias[col] : 0.0f;
        #pragma unroll
        for (int i = 0; i < 4; ++i) {
            int r0 = gm0 + wm*64 + i*16 + quad*4;
            #pragma unroll
            for (int r = 0; r < 4; ++r) {
                float v = (acc[i][j][r] + bb) * scale;
                int m = r0 + r;
                if (mode == 2)      ((float*)out)[(size_t)m*EE + col] = v;
                else if (mode == 1) ((f16*)out)[((size_t)(m & 1)*EE + col)*SQ + (m >> 1)] = (f16)v;
                else                ((f16*)out)[(size_t)m*EE + col] = (f16)v;
            }
        }
    }
}

__global__ __launch_bounds__(256) void k_gemm_qkv(
    const f16* xq, const f16* qw, const float* qb,
    const f16* xk, const f16* kw, const float* kb,
    const f16* xv, const f16* vw, const float* vb,
    f16* Q16, f16* K16, f16* Vt16)
{
    int z = blockIdx.z;
    const f16* A = (z==0) ? xq : (z==1) ? xk : xv;
    const f16* W = (z==0) ? qw : (z==1) ? kw : vw;
    const float* bi = (z==0) ? qb : (z==1) ? kb : vb;
    float sc = (z==0) ? 0.125f * LOG2E : 1.0f;   // fold log2e into Q
    void* o = (z==0) ? (void*)Q16 : (z==1) ? (void*)K16 : (void*)Vt16;
    gemm_body(A, W, bi, sc, o, (z==2) ? 1 : 0);
}

__global__ __launch_bounds__(256) void k_gemm_o(const f16* A, const f16* W, float* out)
{
    gemm_body(A, W, nullptr, 1.0f, out, 2);
}

// ---------------- phase 1: lse2[b,h,q] = log2(sum_k 2^s2) ----------------
// No LDS staging, no in-loop barriers: wave w owns k-cols w*32..+31 of each 128-k tile.
__global__ __launch_bounds__(256, 4) void k_attn_l(
    const f16* __restrict__ Q16, const f16* __restrict__ K16, float* __restrict__ lse2)
{
    __shared__ float red[4][64];
    const int t = threadIdx.x, lane = t & 63, w = t >> 6;
    const int quad = lane >> 4, m16 = lane & 15;
    const int q0 = blockIdx.x * 64, h = blockIdx.y, b = blockIdx.z;

    half8 bq[4][2];
    #pragma unroll
    for (int nt = 0; nt < 4; ++nt)
        #pragma unroll
        for (int dk = 0; dk < 2; ++dk)
            bq[nt][dk] = *(const half8*)&Q16[(size_t)((q0 + nt*16 + m16)*BB + b)*EE + h*DD + dk*32 + quad*8];

    float lsum[4] = {};
    for (int kt = 0; kt < 16; ++kt) {
        half8 ak[2][2];
        #pragma unroll
        for (int mt = 0; mt < 2; ++mt)
            #pragma unroll
            for (int dk = 0; dk < 2; ++dk)
                ak[mt][dk] = *(const half8*)&K16[(size_t)((kt*128 + w*32 + mt*16 + m16)*BB + b)*EE + h*DD + dk*32 + quad*8];
        #pragma unroll
        for (int mt = 0; mt < 2; ++mt)
            #pragma unroll
            for (int nt = 0; nt < 4; ++nt) {
                f32x4 s = {};
                s = mfma16(ak[mt][0], bq[nt][0], s);   // S^T: rows k, cols q
                s = mfma16(ak[mt][1], bq[nt][1], s);
                lsum[nt] += __builtin_amdgcn_exp2f(s[0]) + __builtin_amdgcn_exp2f(s[1])
                          + __builtin_amdgcn_exp2f(s[2]) + __builtin_amdgcn_exp2f(s[3]);
            }
    }
    #pragma unroll
    for (int nt = 0; nt < 4; ++nt) {
        float v = lsum[nt];
        v += __shfl_xor(v, 16, 64);
        v += __shfl_xor(v, 32, 64);
        lsum[nt] = v;
    }
    if (quad == 0)
        #pragma unroll
        for (int nt = 0; nt < 4; ++nt) red[w][nt*16 + m16] = lsum[nt];
    __syncthreads();
    if (t < 64) {
        float v = red[0][t] + red[1][t] + red[2][t] + red[3][t];
        lse2[((size_t)b*HH + h)*SQ + q0 + t] = __log2f(v);
    }
}

// ---------------- phase 2: probs, avg_attn (regs), ctx partials ----------------
// grid (SQ/16, NSLICE, B) = 1024 wgs -> 4 blocks/CU resident (was 2).
// Flattened (h,kt) pipeline: K-frags prefetched one round ahead ACROSS head
// boundaries; V-frags + next-head Q issued before the barrier so the barrier
// drain covers their latency. One barrier per round, double-buffered ps.
__global__ __launch_bounds__(256, 4) void k_attn_main(
    const f16* __restrict__ Q16, const f16* __restrict__ K16, const f16* __restrict__ Vt16,
    const float* __restrict__ lse2, float* __restrict__ ctxp, float* __restrict__ avg_out)
{
    __shared__ f16 ps[2][16][136];
    __shared__ float csh[HH][16];
    const int t = threadIdx.x, lane = t & 63, w = t >> 6;
    const int quad = lane >> 4, m16 = lane & 15;
    const int q0 = blockIdx.x * 16, sl = blockIdx.y, b = blockIdx.z;
    const int ks0 = sl * KSLICE;

    {   // 256 threads load exactly 16 heads x 16 q lse values
        int hh = t >> 4, qq = t & 15;
        csh[hh][qq] = lse2[((size_t)b*HH + hh)*SQ + q0 + qq];
    }

    float avg_r[KT_IN][8] = {};   // lane-exclusive (q,k) slots, accumulated over h

    // initial fragments for (h=0, kt=0)
    half8 ak[2][2][2], bq[2], bv[4];
    #pragma unroll
    for (int mt = 0; mt < 2; ++mt)
        #pragma unroll
        for (int dk = 0; dk < 2; ++dk)
            ak[0][mt][dk] = *(const half8*)&K16[(size_t)((ks0 + w*32 + mt*16 + m16)*BB + b)*EE + dk*32 + quad*8];
    #pragma unroll
    for (int dk = 0; dk < 2; ++dk)
        bq[dk] = *(const half8*)&Q16[(size_t)((q0 + m16)*BB + b)*EE + dk*32 + quad*8];

    __syncthreads();   // csh ready

    f32x4 acc[2] = {};

    for (int rp = 0; rp < 8; ++rp) {       // 8 outer x 8 unrolled = 64 rounds
        #pragma unroll
        for (int ri = 0; ri < 8; ++ri) {   // all mod-indices compile-time
            const int round = rp*8 + ri;
            const int h  = rp*2 + (ri >> 2);      // head 0..15
            const int kt = ri & 3;                // 128-k tile within slice
            const int cur = ri & 1, nxt = cur ^ 1;
            const bool last = (rp == 7) && (ri == 7);

            // prefetch next round's K fragments (wraps across head boundary)
            if (!last) {
                const int rn  = round + 1;
                const int hn  = rn >> 2, ktn = rn & 3;
                #pragma unroll
                for (int mt = 0; mt < 2; ++mt)
                    #pragma unroll
                    for (int dk = 0; dk < 2; ++dk)
                        ak[nxt][mt][dk] = *(const half8*)&K16[(size_t)((ks0 + ktn*128 + w*32 + mt*16 + m16)*BB + b)*EE + hn*DD + dk*32 + quad*8];
            }

            const float c0 = csh[h][m16];
            // S^T = K.Q^T: lane holds 4 consecutive k (rows), fixed q (col=m16)
            #pragma unroll
            for (int mt = 0; mt < 2; ++mt) {
                f32x4 s = {};
                s = mfma16(ak[cur][mt][0], bq[0], s);
                s = mfma16(ak[cur][mt][1], bq[1], s);
                half4 ph;
                #pragma unroll
                for (int r = 0; r < 4; ++r) {
                    float p = __builtin_amdgcn_exp2f(s[r] - c0);
                    avg_r[kt][mt*4 + r] += p;
                    ph[r] = (f16)p;
                }
                *(half4*)&ps[cur][m16][w*32 + mt*16 + quad*4] = ph;
            }

            // current round's V fragments (consumed after the barrier)
            #pragma unroll
            for (int ks = 0; ks < 4; ++ks)
                bv[ks] = *(const half8*)&Vt16[((size_t)b*EE + h*DD + w*16 + m16)*SQ + ks0 + kt*128 + ks*32 + quad*8];

            // next head's Q fragments (bq dead after the QK above)
            if ((ri == 3 || ri == 7) && !last) {
                const int hn = (round + 1) >> 2;
                #pragma unroll
                for (int dk = 0; dk < 2; ++dk)
                    bq[dk] = *(const half8*)&Q16[(size_t)((q0 + m16)*BB + b)*EE + hn*DD + dk*32 + quad*8];
            }

            __syncthreads();   // ps[cur] complete (double-buffer: 1 barrier/round)

            // PV: ctx[16q x 64d] += P @ V; wave w owns d = w*16..+15
            {
                f32x4 c4 = acc[(ri >> 2) & 1];
                #pragma unroll
                for (int ks = 0; ks < 4; ++ks) {
                    half8 ap = *(half8*)&ps[cur][m16][ks*32 + quad*8];
                    c4 = mfma16(ap, bv[ks], c4);
                }
                acc[(ri >> 2) & 1] = c4;
            }

            // flush 2 heads of ctx partials (fp32) every 8 rounds
            if (ri == 7) {
                #pragma unroll
                for (int hh2 = 0; hh2 < 2; ++hh2) {
                    #pragma unroll
                    for (int r = 0; r < 4; ++r) {
                        int q = q0 + quad*4 + r;
                        ctxp[(size_t)sl*MM*EE + ((size_t)q*BB + b)*EE + (h - 1 + hh2)*DD + w*16 + m16] = acc[hh2][r];
                    }
                    acc[hh2] = (f32x4){};
                }
            }
        }
    }

    // write owned avg tile (float4 stores)
    #pragma unroll
    for (int kt = 0; kt < KT_IN; ++kt)
        #pragma unroll
        for (int mt = 0; mt < 2; ++mt) {
            int q = q0 + m16;
            int k = ks0 + kt*128 + w*32 + mt*16 + quad*4;
            float4 v = { avg_r[kt][mt*4+0]*(1.0f/HH), avg_r[kt][mt*4+1]*(1.0f/HH),
                         avg_r[kt][mt*4+2]*(1.0f/HH), avg_r[kt][mt*4+3]*(1.0f/HH) };
            *(float4*)&avg_out[((size_t)b*SQ + q)*SQ + k] = v;
        }
}

// ---------------- ctx partial reduction: fp32 x NSLICE -> f16 ----------------
__global__ void k_ctx_red(const float* __restrict__ ctxp, f16* __restrict__ ctx16) {
    size_t i = ((size_t)blockIdx.x * 256 + threadIdx.x) * 4;
    float4 s = *(const float4*)&ctxp[i];
    #pragma unroll
    for (int sl = 1; sl < NSLICE; ++sl) {
        float4 v = *(const float4*)&ctxp[(size_t)sl*MM*EE + i];
        s.x += v.x; s.y += v.y; s.z += v.z; s.w += v.w;
    }
    half4 o = {(f16)s.x, (f16)s.y, (f16)s.z, (f16)s.w};
    *(half4*)&ctx16[i] = o;
}

// ---------------- launch ----------------
extern "C" void kernel_launch(void* const* d_in, const int* in_sizes, int n_in,
                              void* d_out, int out_size, void* d_ws, size_t ws_size,
                              hipStream_t stream) {
    const float* query    = (const float*)d_in[0];
    const float* key      = (const float*)d_in[1];
    const float* value    = (const float*)d_in[2];
    const float* q_w      = (const float*)d_in[3];
    const float* q_b      = (const float*)d_in[4];
    const float* k_w      = (const float*)d_in[5];
    const float* k_b      = (const float*)d_in[6];
    const float* v_w      = (const float*)d_in[7];
    const float* v_b      = (const float*)d_in[8];
    const float* o_w_mean = (const float*)d_in[9];
    const float* o_w_lgstd= (const float*)d_in[10];
    const float* eps      = (const float*)d_in[11];
    float* out = (float*)d_out;                  // [S,B,E] fp32
    float* avg = out + (size_t)MM * EE;          // [B,S,S] fp32

    const size_t EWN = (size_t)EE*EE;   // 1M
    const size_t XWN = (size_t)MM*EE;   // 4M
    f16* qw16  = (f16*)d_ws;
    f16* kw16  = qw16 + EWN;
    f16* vw16  = kw16 + EWN;
    f16* ow16  = vw16 + EWN;
    f16* Q16   = ow16 + EWN;
    f16* K16   = Q16  + XWN;
    f16* Vt16  = K16  + XWN;
    f16* ctx16 = Vt16 + XWN;
    float* lse2 = (float*)(ctx16 + XWN);             // B*H*S fp32
    f16* xq16  = (f16*)(lse2 + (size_t)BB*HH*SQ);
    f16* xk16  = xq16 + XWN;
    f16* xv16  = xk16 + XWN;
    // ctxp aliases xq/xk/xv (dead after projections) and extends beyond: NSLICE*16MB
    float* ctxp = (float*)xq16;

    k_elem<<<dim3(XWN/1024, 7), 256, 0, stream>>>(q_w, k_w, v_w, query, key, value,
        o_w_mean, o_w_lgstd, eps, qw16, kw16, vw16, xq16, xk16, xv16, ow16);

    k_gemm_qkv<<<dim3(MM/128, EE/64, 3), 256, 0, stream>>>(
        xq16, qw16, q_b, xk16, kw16, k_b, xv16, vw16, v_b, Q16, K16, Vt16);

    k_attn_l   <<<dim3(SQ/64, HH, BB), 256, 0, stream>>>(Q16, K16, lse2);
    k_attn_main<<<dim3(SQ/16, NSLICE, BB), 256, 0, stream>>>(Q16, K16, Vt16, lse2, ctxp, avg);
    k_ctx_red  <<<XWN/1024, 256, 0, stream>>>(ctxp, ctx16);

    k_gemm_o<<<dim3(MM/128, EE/64), 256, 0, stream>>>(ctx16, ow16, out);
}

// Round 4
// 394.761 us; speedup vs baseline: 1.3145x; 1.3145x over previous
//
#include <hip/hip_runtime.h>

#define SQ 2048
#define BB 2
#define EE 1024
#define HH 16
#define DD 64
#define MM (SQ*BB)          // 4096 composite rows (s*B + b)
#define NSLICE 4
#define KSLICE (SQ/NSLICE)  // 512 k per attn_main wg
#define KT_IN (KSLICE/128)  // 4 kt tiles of 128
#define LOG2E 1.44269504f

typedef _Float16 f16;
typedef _Float16 half8 __attribute__((ext_vector_type(8)));
typedef _Float16 half4 __attribute__((ext_vector_type(4)));
typedef float f32x4 __attribute__((ext_vector_type(4)));

static __device__ __forceinline__ f32x4 mfma16(half8 a, half8 b, f32x4 c) {
    return __builtin_amdgcn_mfma_f32_16x16x32_f16(a, b, c, 0, 0, 0);
}

// async global->LDS, 16B per lane (GEMM staging only)
static __device__ __forceinline__ void gload16(const f16* g, f16* l) {
    __builtin_amdgcn_global_load_lds(
        (const __attribute__((address_space(1))) unsigned int*)g,
        (__attribute__((address_space(3))) unsigned int*)l, 16, 0, 0);
}

// ---------------- fused elementwise converts ----------------
__global__ void k_elem(const float* __restrict__ q_w, const float* __restrict__ k_w,
                       const float* __restrict__ v_w, const float* __restrict__ query,
                       const float* __restrict__ key, const float* __restrict__ value,
                       const float* __restrict__ owm, const float* __restrict__ owl,
                       const float* __restrict__ eps,
                       f16* qw16, f16* kw16, f16* vw16,
                       f16* xq16, f16* xk16, f16* xv16, f16* ow16)
{
    int y = blockIdx.y;
    size_t i = ((size_t)blockIdx.x * 256 + threadIdx.x) * 4;
    if (y < 3) {
        if (i >= (size_t)EE*EE) return;
        const float* s = (y==0) ? q_w : (y==1) ? k_w : v_w;
        f16* d = (y==0) ? qw16 : (y==1) ? kw16 : vw16;
        float4 v = *(const float4*)&s[i];
        half4 o = {(f16)v.x, (f16)v.y, (f16)v.z, (f16)v.w};
        *(half4*)&d[i] = o;
    } else if (y < 6) {
        const float* s = (y==3) ? query : (y==4) ? key : value;
        f16* d = (y==3) ? xq16 : (y==4) ? xk16 : xv16;
        float4 v = *(const float4*)&s[i];
        half4 o = {(f16)v.x, (f16)v.y, (f16)v.z, (f16)v.w};
        *(half4*)&d[i] = o;
    } else {
        if (i >= (size_t)EE*EE) return;
        float4 m = *(const float4*)&owm[i];
        float4 l = *(const float4*)&owl[i];
        float4 e = *(const float4*)&eps[i];
        half4 o = {(f16)(m.x + e.x * __expf(l.x)), (f16)(m.y + e.y * __expf(l.y)),
                   (f16)(m.z + e.z * __expf(l.z)), (f16)(m.w + e.w * __expf(l.w))};
        *(half4*)&ow16[i] = o;
    }
}

// ---------------- GEMM body: C[M,N] = (A[M,K] @ W[N,K]^T + bias) * scale ----------------
// 128x64 tile, BK=32. mode: 0 = f16 row-major, 1 = f16 V-transposed [b][d][s], 2 = f32.
__device__ __forceinline__ void gemm_body(
    const f16* __restrict__ A, const f16* __restrict__ W,
    const float* __restrict__ bias, float scale, void* __restrict__ out, int mode)
{
    __shared__ f16 As[128*32];
    __shared__ f16 Bs[64*32];
    int t = threadIdx.x, lane = t & 63, w = t >> 6;
    int quad = lane >> 4, m16 = lane & 15;
    int wm = w >> 1, wn = w & 1;
    int gm0 = blockIdx.x * 128, gn0 = blockIdx.y * 64;
    int arow = lane >> 2, apch = lane & 3;
    f32x4 acc[4][2] = {};
    for (int kt = 0; kt < EE; kt += 32) {
        #pragma unroll
        for (int j = 0; j < 2; ++j) {
            int row = w*32 + j*16 + arow;
            int lch = apch ^ (row & 3);
            gload16(&A[(size_t)(gm0+row)*EE + kt + lch*8], &As[row*32 + apch*8]);
        }
        {
            int row = w*16 + arow;
            int lch = apch ^ (row & 3);
            gload16(&W[(size_t)(gn0+row)*EE + kt + lch*8], &Bs[row*32 + apch*8]);
        }
        __syncthreads();
        int cs = (quad ^ (m16 & 3)) * 8;
        half8 af[4], bf[2];
        #pragma unroll
        for (int i = 0; i < 4; ++i) af[i] = *(half8*)&As[(wm*64 + i*16 + m16)*32 + cs];
        #pragma unroll
        for (int j = 0; j < 2; ++j) bf[j] = *(half8*)&Bs[(wn*32 + j*16 + m16)*32 + cs];
        #pragma unroll
        for (int i = 0; i < 4; ++i)
            #pragma unroll
            for (int j = 0; j < 2; ++j)
                acc[i][j] = mfma16(af[i], bf[j], acc[i][j]);
        __syncthreads();
    }
    #pragma unroll
    for (int j = 0; j < 2; ++j) {
        int col = gn0 + wn*32 + j*16 + m16;
        float bb = bias ? bias[col] : 0.0f;
        #pragma unroll
        for (int i = 0; i < 4; ++i) {
            int r0 = gm0 + wm*64 + i*16 + quad*4;
            #pragma unroll
            for (int r = 0; r < 4; ++r) {
                float v = (acc[i][j][r] + bb) * scale;
                int m = r0 + r;
                if (mode == 2)      ((float*)out)[(size_t)m*EE + col] = v;
                else if (mode == 1) ((f16*)out)[((size_t)(m & 1)*EE + col)*SQ + (m >> 1)] = (f16)v;
                else                ((f16*)out)[(size_t)m*EE + col] = (f16)v;
            }
        }
    }
}

__global__ __launch_bounds__(256) void k_gemm_qkv(
    const f16* xq, const f16* qw, const float* qb,
    const f16* xk, const f16* kw, const float* kb,
    const f16* xv, const f16* vw, const float* vb,
    f16* Q16, f16* K16, f16* Vt16)
{
    int z = blockIdx.z;
    const f16* A = (z==0) ? xq : (z==1) ? xk : xv;
    const f16* W = (z==0) ? qw : (z==1) ? kw : vw;
    const float* bi = (z==0) ? qb : (z==1) ? kb : vb;
    float sc = (z==0) ? 0.125f * LOG2E : 1.0f;   // fold log2e into Q
    void* o = (z==0) ? (void*)Q16 : (z==1) ? (void*)K16 : (void*)Vt16;
    gemm_body(A, W, bi, sc, o, (z==2) ? 1 : 0);
}

__global__ __launch_bounds__(256) void k_gemm_o(const f16* A, const f16* W, float* out)
{
    gemm_body(A, W, nullptr, 1.0f, out, 2);
}

// ---------------- phase 1: lse2[b,h,q] = log2(sum_k 2^s2) ----------------
// No LDS staging, no in-loop barriers: wave w owns k-cols w*32..+31 of each 128-k tile.
__global__ __launch_bounds__(256, 4) void k_attn_l(
    const f16* __restrict__ Q16, const f16* __restrict__ K16, float* __restrict__ lse2)
{
    __shared__ float red[4][64];
    const int t = threadIdx.x, lane = t & 63, w = t >> 6;
    const int quad = lane >> 4, m16 = lane & 15;
    const int q0 = blockIdx.x * 64, h = blockIdx.y, b = blockIdx.z;

    half8 bq[4][2];
    #pragma unroll
    for (int nt = 0; nt < 4; ++nt)
        #pragma unroll
        for (int dk = 0; dk < 2; ++dk)
            bq[nt][dk] = *(const half8*)&Q16[(size_t)((q0 + nt*16 + m16)*BB + b)*EE + h*DD + dk*32 + quad*8];

    float lsum[4] = {};
    for (int kt = 0; kt < 16; ++kt) {
        half8 ak[2][2];
        #pragma unroll
        for (int mt = 0; mt < 2; ++mt)
            #pragma unroll
            for (int dk = 0; dk < 2; ++dk)
                ak[mt][dk] = *(const half8*)&K16[(size_t)((kt*128 + w*32 + mt*16 + m16)*BB + b)*EE + h*DD + dk*32 + quad*8];
        #pragma unroll
        for (int mt = 0; mt < 2; ++mt)
            #pragma unroll
            for (int nt = 0; nt < 4; ++nt) {
                f32x4 s = {};
                s = mfma16(ak[mt][0], bq[nt][0], s);   // S^T: rows k, cols q
                s = mfma16(ak[mt][1], bq[nt][1], s);
                lsum[nt] += __builtin_amdgcn_exp2f(s[0]) + __builtin_amdgcn_exp2f(s[1])
                          + __builtin_amdgcn_exp2f(s[2]) + __builtin_amdgcn_exp2f(s[3]);
            }
    }
    #pragma unroll
    for (int nt = 0; nt < 4; ++nt) {
        float v = lsum[nt];
        v += __shfl_xor(v, 16, 64);
        v += __shfl_xor(v, 32, 64);
        lsum[nt] = v;
    }
    if (quad == 0)
        #pragma unroll
        for (int nt = 0; nt < 4; ++nt) red[w][nt*16 + m16] = lsum[nt];
    __syncthreads();
    if (t < 64) {
        float v = red[0][t] + red[1][t] + red[2][t] + red[3][t];
        lse2[((size_t)b*HH + h)*SQ + q0 + t] = __log2f(v);
    }
}

// ---------------- phase 2: probs, avg_attn (regs), ctx partials ----------------
// grid (SQ/32, NSLICE, B) = 512. K/V frags direct from global (wave-exclusive rows/cols),
// software-pipelined. S^T layout -> ps writes are ds_write_b64. Double-buffered ps.
// In-loop barrier: s_waitcnt lgkmcnt(0) (via __builtin_amdgcn_s_waitcnt(0xC07F)) +
// s_barrier, bracketed by sched_barrier(0) (rule #18). The LDS exchange needs lgkm
// ordering only; the register-destined K/V/Q prefetches stay in flight across the
// barrier (their first use is guarded by compiler-inserted vmcnt(N)). __syncthreads()
// would drain vmcnt(0) every round, serializing each round on a full L2 round-trip.
__global__ __launch_bounds__(256, 2) void k_attn_main(
    const f16* __restrict__ Q16, const f16* __restrict__ K16, const f16* __restrict__ Vt16,
    const float* __restrict__ lse2, float* __restrict__ ctxp, float* __restrict__ avg_out)
{
    __shared__ f16 ps[2][32][136];
    __shared__ float csh[HH][32];
    const int t = threadIdx.x, lane = t & 63, w = t >> 6;
    const int quad = lane >> 4, m16 = lane & 15;
    const int q0 = blockIdx.x * 32, sl = blockIdx.y, b = blockIdx.z;
    const int ks0 = sl * KSLICE;

    for (int i = t; i < HH*32; i += 256) {
        int hh = i >> 5, qq = i & 31;
        csh[hh][qq] = lse2[((size_t)b*HH + hh)*SQ + q0 + qq];
    }
    __syncthreads();

    float avg_r[KT_IN][16] = {};   // lane-exclusive (q,k) slots, accumulated over h

    for (int hp = 0; hp < 8; ++hp) {
        f32x4 acc[2][2] = {};
        for (int hh2 = 0; hh2 < 2; ++hh2) {
            const int h = hp*2 + hh2;
            half8 bq[2][2];
            #pragma unroll
            for (int nt = 0; nt < 2; ++nt)
                #pragma unroll
                for (int dk = 0; dk < 2; ++dk)
                    bq[nt][dk] = *(const half8*)&Q16[(size_t)((q0 + nt*16 + m16)*BB + b)*EE + h*DD + dk*32 + quad*8];
            const float c01[2] = { csh[h][m16], csh[h][16 + m16] };

            half8 ak[2][2][2], bv[2][4];
            #pragma unroll
            for (int mt = 0; mt < 2; ++mt)
                #pragma unroll
                for (int dk = 0; dk < 2; ++dk)
                    ak[0][mt][dk] = *(const half8*)&K16[(size_t)((ks0 + w*32 + mt*16 + m16)*BB + b)*EE + h*DD + dk*32 + quad*8];
            #pragma unroll
            for (int ks = 0; ks < 4; ++ks)
                bv[0][ks] = *(const half8*)&Vt16[((size_t)b*EE + h*DD + w*16 + m16)*SQ + ks0 + ks*32 + quad*8];

            #pragma unroll
            for (int kt = 0; kt < KT_IN; ++kt) {
                const int cur = kt & 1, nxt = cur ^ 1;
                if (kt + 1 < KT_IN) {   // prefetch next tile's fragments
                    #pragma unroll
                    for (int mt = 0; mt < 2; ++mt)
                        #pragma unroll
                        for (int dk = 0; dk < 2; ++dk)
                            ak[nxt][mt][dk] = *(const half8*)&K16[(size_t)((ks0 + (kt+1)*128 + w*32 + mt*16 + m16)*BB + b)*EE + h*DD + dk*32 + quad*8];
                    #pragma unroll
                    for (int ks = 0; ks < 4; ++ks)
                        bv[nxt][ks] = *(const half8*)&Vt16[((size_t)b*EE + h*DD + w*16 + m16)*SQ + ks0 + (kt+1)*128 + ks*32 + quad*8];
                }
                // S^T = K·Q^T: lane holds 4 consecutive k (rows), fixed q (col)
                #pragma unroll
                for (int mt = 0; mt < 2; ++mt)
                    #pragma unroll
                    for (int nt = 0; nt < 2; ++nt) {
                        f32x4 s = {};
                        s = mfma16(ak[cur][mt][0], bq[nt][0], s);
                        s = mfma16(ak[cur][mt][1], bq[nt][1], s);
                        half4 ph;
                        #pragma unroll
                        for (int r = 0; r < 4; ++r) {
                            float p = __builtin_amdgcn_exp2f(s[r] - c01[nt]);
                            avg_r[kt][mt*8 + nt*4 + r] += p;
                            ph[r] = (f16)p;
                        }
                        *(half4*)&ps[cur][nt*16 + m16][w*32 + mt*16 + quad*4] = ph;
                    }
                // ps[cur] exchange barrier: order LDS only (lgkmcnt(0)), keep global
                // prefetches in flight. sched_barrier(0) pins code motion (rule #18).
                __builtin_amdgcn_sched_barrier(0);
                __builtin_amdgcn_s_waitcnt(0xC07F);   // lgkmcnt(0), vmcnt/expcnt = max
                __builtin_amdgcn_s_barrier();
                __builtin_amdgcn_sched_barrier(0);
                // PV: ctx[32q x 64d] += P @ V; wave w owns d = w*16..+15
                #pragma unroll
                for (int qt = 0; qt < 2; ++qt) {
                    f32x4 c4 = acc[hh2][qt];
                    #pragma unroll
                    for (int ks = 0; ks < 4; ++ks) {
                        half8 ap = *(half8*)&ps[cur][qt*16 + m16][ks*32 + quad*8];
                        c4 = mfma16(ap, bv[cur][ks], c4);
                    }
                    acc[hh2][qt] = c4;
                }
            }
        }
        // flush 2 heads of ctx partials (fp32)
        #pragma unroll
        for (int hh2 = 0; hh2 < 2; ++hh2)
            #pragma unroll
            for (int qt = 0; qt < 2; ++qt)
                #pragma unroll
                for (int r = 0; r < 4; ++r) {
                    int q = q0 + qt*16 + quad*4 + r;
                    ctxp[(size_t)sl*MM*EE + ((size_t)q*BB + b)*EE + (hp*2 + hh2)*DD + w*16 + m16] = acc[hh2][qt][r];
                }
    }
    // write owned avg tile (float4 stores)
    #pragma unroll
    for (int kt = 0; kt < KT_IN; ++kt)
        #pragma unroll
        for (int mt = 0; mt < 2; ++mt)
            #pragma unroll
            for (int nt = 0; nt < 2; ++nt) {
                int q = q0 + nt*16 + m16;
                int k = ks0 + kt*128 + w*32 + mt*16 + quad*4;
                float4 v = { avg_r[kt][mt*8+nt*4+0]*(1.0f/HH), avg_r[kt][mt*8+nt*4+1]*(1.0f/HH),
                             avg_r[kt][mt*8+nt*4+2]*(1.0f/HH), avg_r[kt][mt*8+nt*4+3]*(1.0f/HH) };
                *(float4*)&avg_out[((size_t)b*SQ + q)*SQ + k] = v;
            }
}

// ---------------- ctx partial reduction: fp32 x NSLICE -> f16 ----------------
__global__ void k_ctx_red(const float* __restrict__ ctxp, f16* __restrict__ ctx16) {
    size_t i = ((size_t)blockIdx.x * 256 + threadIdx.x) * 4;
    float4 s = *(const float4*)&ctxp[i];
    #pragma unroll
    for (int sl = 1; sl < NSLICE; ++sl) {
        float4 v = *(const float4*)&ctxp[(size_t)sl*MM*EE + i];
        s.x += v.x; s.y += v.y; s.z += v.z; s.w += v.w;
    }
    half4 o = {(f16)s.x, (f16)s.y, (f16)s.z, (f16)s.w};
    *(half4*)&ctx16[i] = o;
}

// ---------------- launch ----------------
extern "C" void kernel_launch(void* const* d_in, const int* in_sizes, int n_in,
                              void* d_out, int out_size, void* d_ws, size_t ws_size,
                              hipStream_t stream) {
    const float* query    = (const float*)d_in[0];
    const float* key      = (const float*)d_in[1];
    const float* value    = (const float*)d_in[2];
    const float* q_w      = (const float*)d_in[3];
    const float* q_b      = (const float*)d_in[4];
    const float* k_w      = (const float*)d_in[5];
    const float* k_b      = (const float*)d_in[6];
    const float* v_w      = (const float*)d_in[7];
    const float* v_b      = (const float*)d_in[8];
    const float* o_w_mean = (const float*)d_in[9];
    const float* o_w_lgstd= (const float*)d_in[10];
    const float* eps      = (const float*)d_in[11];
    float* out = (float*)d_out;                  // [S,B,E] fp32
    float* avg = out + (size_t)MM * EE;          // [B,S,S] fp32

    const size_t EWN = (size_t)EE*EE;   // 1M
    const size_t XWN = (size_t)MM*EE;   // 4M
    f16* qw16  = (f16*)d_ws;
    f16* kw16  = qw16 + EWN;
    f16* vw16  = kw16 + EWN;
    f16* ow16  = vw16 + EWN;
    f16* Q16   = ow16 + EWN;
    f16* K16   = Q16  + XWN;
    f16* Vt16  = K16  + XWN;
    f16* ctx16 = Vt16 + XWN;
    float* lse2 = (float*)(ctx16 + XWN);             // B*H*S fp32
    f16* xq16  = (f16*)(lse2 + (size_t)BB*HH*SQ);
    f16* xk16  = xq16 + XWN;
    f16* xv16  = xk16 + XWN;
    // ctxp aliases xq/xk/xv (dead after projections) and extends beyond: NSLICE*16MB
    float* ctxp = (float*)xq16;

    k_elem<<<dim3(XWN/1024, 7), 256, 0, stream>>>(q_w, k_w, v_w, query, key, value,
        o_w_mean, o_w_lgstd, eps, qw16, kw16, vw16, xq16, xk16, xv16, ow16);

    k_gemm_qkv<<<dim3(MM/128, EE/64, 3), 256, 0, stream>>>(
        xq16, qw16, q_b, xk16, kw16, k_b, xv16, vw16, v_b, Q16, K16, Vt16);

    k_attn_l   <<<dim3(SQ/64, HH, BB), 256, 0, stream>>>(Q16, K16, lse2);
    k_attn_main<<<dim3(SQ/32, NSLICE, BB), 256, 0, stream>>>(Q16, K16, Vt16, lse2, ctxp, avg);
    k_ctx_red  <<<XWN/1024, 256, 0, stream>>>(ctxp, ctx16);

    k_gemm_o<<<dim3(MM/128, EE/64), 256, 0, stream>>>(ctx16, ow16, out);
}

// Round 5
// 371.463 us; speedup vs baseline: 1.3970x; 1.0627x over previous
//
#include <hip/hip_runtime.h>

#define SQ 2048
#define BB 2
#define EE 1024
#define HH 16
#define DD 64
#define MM (SQ*BB)          // 4096 composite rows (s*B + b)
#define NSLICE 4
#define KSLICE (SQ/NSLICE)  // 512 k per attn_main wg
#define KT_IN (KSLICE/128)  // 4 kt tiles of 128
#define LOG2E 1.44269504f

typedef _Float16 f16;
typedef _Float16 half8 __attribute__((ext_vector_type(8)));
typedef _Float16 half4 __attribute__((ext_vector_type(4)));
typedef float f32x4 __attribute__((ext_vector_type(4)));

static __device__ __forceinline__ f32x4 mfma16(half8 a, half8 b, f32x4 c) {
    return __builtin_amdgcn_mfma_f32_16x16x32_f16(a, b, c, 0, 0, 0);
}

// async global->LDS, 16B per lane (GEMM staging only)
static __device__ __forceinline__ void gload16(const f16* g, f16* l) {
    __builtin_amdgcn_global_load_lds(
        (const __attribute__((address_space(1))) unsigned int*)g,
        (__attribute__((address_space(3))) unsigned int*)l, 16, 0, 0);
}

// ---------------- fused elementwise converts ----------------
__global__ void k_elem(const float* __restrict__ q_w, const float* __restrict__ k_w,
                       const float* __restrict__ v_w, const float* __restrict__ query,
                       const float* __restrict__ key, const float* __restrict__ value,
                       const float* __restrict__ owm, const float* __restrict__ owl,
                       const float* __restrict__ eps,
                       f16* qw16, f16* kw16, f16* vw16,
                       f16* xq16, f16* xk16, f16* xv16, f16* ow16)
{
    int y = blockIdx.y;
    size_t i = ((size_t)blockIdx.x * 256 + threadIdx.x) * 4;
    if (y < 3) {
        if (i >= (size_t)EE*EE) return;
        const float* s = (y==0) ? q_w : (y==1) ? k_w : v_w;
        f16* d = (y==0) ? qw16 : (y==1) ? kw16 : vw16;
        float4 v = *(const float4*)&s[i];
        half4 o = {(f16)v.x, (f16)v.y, (f16)v.z, (f16)v.w};
        *(half4*)&d[i] = o;
    } else if (y < 6) {
        const float* s = (y==3) ? query : (y==4) ? key : value;
        f16* d = (y==3) ? xq16 : (y==4) ? xk16 : xv16;
        float4 v = *(const float4*)&s[i];
        half4 o = {(f16)v.x, (f16)v.y, (f16)v.z, (f16)v.w};
        *(half4*)&d[i] = o;
    } else {
        if (i >= (size_t)EE*EE) return;
        float4 m = *(const float4*)&owm[i];
        float4 l = *(const float4*)&owl[i];
        float4 e = *(const float4*)&eps[i];
        half4 o = {(f16)(m.x + e.x * __expf(l.x)), (f16)(m.y + e.y * __expf(l.y)),
                   (f16)(m.z + e.z * __expf(l.z)), (f16)(m.w + e.w * __expf(l.w))};
        *(half4*)&ow16[i] = o;
    }
}

// ---------------- GEMM body: C[M,N] = (A[M,K] @ W[N,K]^T + bias) * scale ----------------
// 128x64 tile, BK=32.
// mode 0: f16 -> [b][h][s][d]            (attention-coalesced Q/K)
// mode 1: f16 -> [b][h][s/32][d][32]     (attention-coalesced V^T, k-tiled)
// mode 2: f32 row-major [m][col]
__device__ __forceinline__ void gemm_body(
    const f16* __restrict__ A, const f16* __restrict__ W,
    const float* __restrict__ bias, float scale, void* __restrict__ out, int mode)
{
    __shared__ f16 As[128*32];
    __shared__ f16 Bs[64*32];
    int t = threadIdx.x, lane = t & 63, w = t >> 6;
    int quad = lane >> 4, m16 = lane & 15;
    int wm = w >> 1, wn = w & 1;
    int gm0 = blockIdx.x * 128, gn0 = blockIdx.y * 64;
    int arow = lane >> 2, apch = lane & 3;
    f32x4 acc[4][2] = {};
    for (int kt = 0; kt < EE; kt += 32) {
        #pragma unroll
        for (int j = 0; j < 2; ++j) {
            int row = w*32 + j*16 + arow;
            int lch = apch ^ (row & 3);
            gload16(&A[(size_t)(gm0+row)*EE + kt + lch*8], &As[row*32 + apch*8]);
        }
        {
            int row = w*16 + arow;
            int lch = apch ^ (row & 3);
            gload16(&W[(size_t)(gn0+row)*EE + kt + lch*8], &Bs[row*32 + apch*8]);
        }
        __syncthreads();
        int cs = (quad ^ (m16 & 3)) * 8;
        half8 af[4], bf[2];
        #pragma unroll
        for (int i = 0; i < 4; ++i) af[i] = *(half8*)&As[(wm*64 + i*16 + m16)*32 + cs];
        #pragma unroll
        for (int j = 0; j < 2; ++j) bf[j] = *(half8*)&Bs[(wn*32 + j*16 + m16)*32 + cs];
        #pragma unroll
        for (int i = 0; i < 4; ++i)
            #pragma unroll
            for (int j = 0; j < 2; ++j)
                acc[i][j] = mfma16(af[i], bf[j], acc[i][j]);
        __syncthreads();
    }
    #pragma unroll
    for (int j = 0; j < 2; ++j) {
        int col = gn0 + wn*32 + j*16 + m16;
        int h = col >> 6, d = col & 63;
        float bb = bias ? bias[col] : 0.0f;
        #pragma unroll
        for (int i = 0; i < 4; ++i) {
            int r0 = gm0 + wm*64 + i*16 + quad*4;
            #pragma unroll
            for (int r = 0; r < 4; ++r) {
                float v = (acc[i][j][r] + bb) * scale;
                int m = r0 + r;
                int s = m >> 1, b = m & 1;
                if (mode == 2)
                    ((float*)out)[(size_t)m*EE + col] = v;
                else if (mode == 1)
                    ((f16*)out)[((((size_t)b*HH + h)*(SQ/32) + (s >> 5))*DD + d)*32 + (s & 31)] = (f16)v;
                else
                    ((f16*)out)[(((size_t)b*HH + h)*SQ + s)*DD + d] = (f16)v;
            }
        }
    }
}

__global__ __launch_bounds__(256) void k_gemm_qkv(
    const f16* xq, const f16* qw, const float* qb,
    const f16* xk, const f16* kw, const float* kb,
    const f16* xv, const f16* vw, const float* vb,
    f16* Q16, f16* K16, f16* Vt16)
{
    int z = blockIdx.z;
    const f16* A = (z==0) ? xq : (z==1) ? xk : xv;
    const f16* W = (z==0) ? qw : (z==1) ? kw : vw;
    const float* bi = (z==0) ? qb : (z==1) ? kb : vb;
    float sc = (z==0) ? 0.125f * LOG2E : 1.0f;   // fold log2e into Q
    void* o = (z==0) ? (void*)Q16 : (z==1) ? (void*)K16 : (void*)Vt16;
    gemm_body(A, W, bi, sc, o, (z==2) ? 1 : 0);
}

__global__ __launch_bounds__(256) void k_gemm_o(const f16* A, const f16* W, float* out)
{
    gemm_body(A, W, nullptr, 1.0f, out, 2);
}

// ---------------- phase 1: lse2[b,h,q] = log2(sum_k 2^s2) ----------------
// Q16/K16 are [b][h][s][d]: frag loads are dense 1-2KB contiguous spans per wave.
__global__ __launch_bounds__(256, 4) void k_attn_l(
    const f16* __restrict__ Q16, const f16* __restrict__ K16, float* __restrict__ lse2)
{
    __shared__ float red[4][64];
    const int t = threadIdx.x, lane = t & 63, w = t >> 6;
    const int quad = lane >> 4, m16 = lane & 15;
    const int q0 = blockIdx.x * 64, h = blockIdx.y, b = blockIdx.z;
    const f16* Qh = Q16 + ((size_t)b*HH + h)*SQ*DD;
    const f16* Kh = K16 + ((size_t)b*HH + h)*SQ*DD;

    half8 bq[4][2];
    #pragma unroll
    for (int nt = 0; nt < 4; ++nt)
        #pragma unroll
        for (int dk = 0; dk < 2; ++dk)
            bq[nt][dk] = *(const half8*)&Qh[(q0 + nt*16 + m16)*DD + dk*32 + quad*8];

    float lsum[4] = {};
    for (int kt = 0; kt < 16; ++kt) {
        half8 ak[2][2];
        #pragma unroll
        for (int mt = 0; mt < 2; ++mt)
            #pragma unroll
            for (int dk = 0; dk < 2; ++dk)
                ak[mt][dk] = *(const half8*)&Kh[(kt*128 + w*32 + mt*16 + m16)*DD + dk*32 + quad*8];
        #pragma unroll
        for (int mt = 0; mt < 2; ++mt)
            #pragma unroll
            for (int nt = 0; nt < 4; ++nt) {
                f32x4 s = {};
                s = mfma16(ak[mt][0], bq[nt][0], s);   // S^T: rows k, cols q
                s = mfma16(ak[mt][1], bq[nt][1], s);
                lsum[nt] += __builtin_amdgcn_exp2f(s[0]) + __builtin_amdgcn_exp2f(s[1])
                          + __builtin_amdgcn_exp2f(s[2]) + __builtin_amdgcn_exp2f(s[3]);
            }
    }
    #pragma unroll
    for (int nt = 0; nt < 4; ++nt) {
        float v = lsum[nt];
        v += __shfl_xor(v, 16, 64);
        v += __shfl_xor(v, 32, 64);
        lsum[nt] = v;
    }
    if (quad == 0)
        #pragma unroll
        for (int nt = 0; nt < 4; ++nt) red[w][nt*16 + m16] = lsum[nt];
    __syncthreads();
    if (t < 64) {
        float v = red[0][t] + red[1][t] + red[2][t] + red[3][t];
        lse2[((size_t)b*HH + h)*SQ + q0 + t] = __log2f(v);
    }
}

// ---------------- phase 2: probs, avg_attn (regs), ctx partials ----------------
// grid (SQ/32, NSLICE, B) = 512. K/V frags direct from global, software-pipelined.
// Q16/K16 [b][h][s][d], Vt16 [b][h][s/32][d][32]: every frag wave-load is a dense
// contiguous 1-2KB span (was 16x 64B lines at 4KB stride -> transaction-bound).
// In-loop barrier: lgkmcnt(0)-only + s_barrier (T4), global prefetches stay in flight.
__global__ __launch_bounds__(256, 2) void k_attn_main(
    const f16* __restrict__ Q16, const f16* __restrict__ K16, const f16* __restrict__ Vt16,
    const float* __restrict__ lse2, float* __restrict__ ctxp, float* __restrict__ avg_out)
{
    __shared__ f16 ps[2][32][136];
    __shared__ float csh[HH][32];
    const int t = threadIdx.x, lane = t & 63, w = t >> 6;
    const int quad = lane >> 4, m16 = lane & 15;
    const int q0 = blockIdx.x * 32, sl = blockIdx.y, b = blockIdx.z;
    const int ks0 = sl * KSLICE;

    for (int i = t; i < HH*32; i += 256) {
        int hh = i >> 5, qq = i & 31;
        csh[hh][qq] = lse2[((size_t)b*HH + hh)*SQ + q0 + qq];
    }
    __syncthreads();

    float avg_r[KT_IN][16] = {};   // lane-exclusive (q,k) slots, accumulated over h

    for (int hp = 0; hp < 8; ++hp) {
        f32x4 acc[2][2] = {};
        for (int hh2 = 0; hh2 < 2; ++hh2) {
            const int h = hp*2 + hh2;
            const f16* Qh = Q16 + ((size_t)b*HH + h)*SQ*DD;
            const f16* Kh = K16 + ((size_t)b*HH + h)*SQ*DD;
            const f16* Vh = Vt16 + ((size_t)b*HH + h)*(SQ/32)*DD*32;
            half8 bq[2][2];
            #pragma unroll
            for (int nt = 0; nt < 2; ++nt)
                #pragma unroll
                for (int dk = 0; dk < 2; ++dk)
                    bq[nt][dk] = *(const half8*)&Qh[(q0 + nt*16 + m16)*DD + dk*32 + quad*8];
            const float c01[2] = { csh[h][m16], csh[h][16 + m16] };

            half8 ak[2][2][2], bv[2][4];
            #pragma unroll
            for (int mt = 0; mt < 2; ++mt)
                #pragma unroll
                for (int dk = 0; dk < 2; ++dk)
                    ak[0][mt][dk] = *(const half8*)&Kh[(ks0 + w*32 + mt*16 + m16)*DD + dk*32 + quad*8];
            #pragma unroll
            for (int ks = 0; ks < 4; ++ks)
                bv[0][ks] = *(const half8*)&Vh[(((ks0 + ks*32) >> 5)*DD + w*16 + m16)*32 + quad*8];

            #pragma unroll
            for (int kt = 0; kt < KT_IN; ++kt) {
                const int cur = kt & 1, nxt = cur ^ 1;
                if (kt + 1 < KT_IN) {   // prefetch next tile's fragments
                    #pragma unroll
                    for (int mt = 0; mt < 2; ++mt)
                        #pragma unroll
                        for (int dk = 0; dk < 2; ++dk)
                            ak[nxt][mt][dk] = *(const half8*)&Kh[(ks0 + (kt+1)*128 + w*32 + mt*16 + m16)*DD + dk*32 + quad*8];
                    #pragma unroll
                    for (int ks = 0; ks < 4; ++ks)
                        bv[nxt][ks] = *(const half8*)&Vh[(((ks0 + (kt+1)*128 + ks*32) >> 5)*DD + w*16 + m16)*32 + quad*8];
                }
                // S^T = K·Q^T: lane holds 4 consecutive k (rows), fixed q (col)
                #pragma unroll
                for (int mt = 0; mt < 2; ++mt)
                    #pragma unroll
                    for (int nt = 0; nt < 2; ++nt) {
                        f32x4 s = {};
                        s = mfma16(ak[cur][mt][0], bq[nt][0], s);
                        s = mfma16(ak[cur][mt][1], bq[nt][1], s);
                        half4 ph;
                        #pragma unroll
                        for (int r = 0; r < 4; ++r) {
                            float p = __builtin_amdgcn_exp2f(s[r] - c01[nt]);
                            avg_r[kt][mt*8 + nt*4 + r] += p;
                            ph[r] = (f16)p;
                        }
                        *(half4*)&ps[cur][nt*16 + m16][w*32 + mt*16 + quad*4] = ph;
                    }
                // ps[cur] exchange barrier: order LDS only (lgkmcnt(0)), keep global
                // prefetches in flight. sched_barrier(0) pins code motion (rule #18).
                __builtin_amdgcn_sched_barrier(0);
                __builtin_amdgcn_s_waitcnt(0xC07F);   // lgkmcnt(0), vmcnt/expcnt = max
                __builtin_amdgcn_s_barrier();
                __builtin_amdgcn_sched_barrier(0);
                // PV: ctx[32q x 64d] += P @ V; wave w owns d = w*16..+15
                #pragma unroll
                for (int qt = 0; qt < 2; ++qt) {
                    f32x4 c4 = acc[hh2][qt];
                    #pragma unroll
                    for (int ks = 0; ks < 4; ++ks) {
                        half8 ap = *(half8*)&ps[cur][qt*16 + m16][ks*32 + quad*8];
                        c4 = mfma16(ap, bv[cur][ks], c4);
                    }
                    acc[hh2][qt] = c4;
                }
            }
        }
        // flush 2 heads of ctx partials (fp32)
        #pragma unroll
        for (int hh2 = 0; hh2 < 2; ++hh2)
            #pragma unroll
            for (int qt = 0; qt < 2; ++qt)
                #pragma unroll
                for (int r = 0; r < 4; ++r) {
                    int q = q0 + qt*16 + quad*4 + r;
                    ctxp[(size_t)sl*MM*EE + ((size_t)q*BB + b)*EE + (hp*2 + hh2)*DD + w*16 + m16] = acc[hh2][qt][r];
                }
    }
    // write owned avg tile (float4 stores)
    #pragma unroll
    for (int kt = 0; kt < KT_IN; ++kt)
        #pragma unroll
        for (int mt = 0; mt < 2; ++mt)
            #pragma unroll
            for (int nt = 0; nt < 2; ++nt) {
                int q = q0 + nt*16 + m16;
                int k = ks0 + kt*128 + w*32 + mt*16 + quad*4;
                float4 v = { avg_r[kt][mt*8+nt*4+0]*(1.0f/HH), avg_r[kt][mt*8+nt*4+1]*(1.0f/HH),
                             avg_r[kt][mt*8+nt*4+2]*(1.0f/HH), avg_r[kt][mt*8+nt*4+3]*(1.0f/HH) };
                *(float4*)&avg_out[((size_t)b*SQ + q)*SQ + k] = v;
            }
}

// ---------------- ctx partial reduction: fp32 x NSLICE -> f16 ----------------
__global__ void k_ctx_red(const float* __restrict__ ctxp, f16* __restrict__ ctx16) {
    size_t i = ((size_t)blockIdx.x * 256 + threadIdx.x) * 4;
    float4 s = *(const float4*)&ctxp[i];
    #pragma unroll
    for (int sl = 1; sl < NSLICE; ++sl) {
        float4 v = *(const float4*)&ctxp[(size_t)sl*MM*EE + i];
        s.x += v.x; s.y += v.y; s.z += v.z; s.w += v.w;
    }
    half4 o = {(f16)s.x, (f16)s.y, (f16)s.z, (f16)s.w};
    *(half4*)&ctx16[i] = o;
}

// ---------------- launch ----------------
extern "C" void kernel_launch(void* const* d_in, const int* in_sizes, int n_in,
                              void* d_out, int out_size, void* d_ws, size_t ws_size,
                              hipStream_t stream) {
    const float* query    = (const float*)d_in[0];
    const float* key      = (const float*)d_in[1];
    const float* value    = (const float*)d_in[2];
    const float* q_w      = (const float*)d_in[3];
    const float* q_b      = (const float*)d_in[4];
    const float* k_w      = (const float*)d_in[5];
    const float* k_b      = (const float*)d_in[6];
    const float* v_w      = (const float*)d_in[7];
    const float* v_b      = (const float*)d_in[8];
    const float* o_w_mean = (const float*)d_in[9];
    const float* o_w_lgstd= (const float*)d_in[10];
    const float* eps      = (const float*)d_in[11];
    float* out = (float*)d_out;                  // [S,B,E] fp32
    float* avg = out + (size_t)MM * EE;          // [B,S,S] fp32

    const size_t EWN = (size_t)EE*EE;   // 1M
    const size_t XWN = (size_t)MM*EE;   // 4M
    f16* qw16  = (f16*)d_ws;
    f16* kw16  = qw16 + EWN;
    f16* vw16  = kw16 + EWN;
    f16* ow16  = vw16 + EWN;
    f16* Q16   = ow16 + EWN;
    f16* K16   = Q16  + XWN;
    f16* Vt16  = K16  + XWN;
    f16* ctx16 = Vt16 + XWN;
    float* lse2 = (float*)(ctx16 + XWN);             // B*H*S fp32
    f16* xq16  = (f16*)(lse2 + (size_t)BB*HH*SQ);
    f16* xk16  = xq16 + XWN;
    f16* xv16  = xk16 + XWN;
    // ctxp aliases xq/xk/xv (dead after projections) and extends beyond: NSLICE*16MB
    float* ctxp = (float*)xq16;

    k_elem<<<dim3(XWN/1024, 7), 256, 0, stream>>>(q_w, k_w, v_w, query, key, value,
        o_w_mean, o_w_lgstd, eps, qw16, kw16, vw16, xq16, xk16, xv16, ow16);

    k_gemm_qkv<<<dim3(MM/128, EE/64, 3), 256, 0, stream>>>(
        xq16, qw16, q_b, xk16, kw16, k_b, xv16, vw16, v_b, Q16, K16, Vt16);

    k_attn_l   <<<dim3(SQ/64, HH, BB), 256, 0, stream>>>(Q16, K16, lse2);
    k_attn_main<<<dim3(SQ/32, NSLICE, BB), 256, 0, stream>>>(Q16, K16, Vt16, lse2, ctxp, avg);
    k_ctx_red  <<<XWN/1024, 256, 0, stream>>>(ctxp, ctx16);

    k_gemm_o<<<dim3(MM/128, EE/64), 256, 0, stream>>>(ctx16, ow16, out);
}

// Round 6
// 369.130 us; speedup vs baseline: 1.4058x; 1.0063x over previous
//
#include <hip/hip_runtime.h>

#define SQ 2048
#define BB 2
#define EE 1024
#define HH 16
#define DD 64
#define MM (SQ*BB)          // 4096 composite rows (s*B + b)
#define NSLICE 4
#define KSLICE (SQ/NSLICE)  // 512 k per attn_main wg
#define KT_IN (KSLICE/128)  // 4 kt tiles of 128
#define LOG2E 1.44269504f

typedef _Float16 f16;
typedef _Float16 half8 __attribute__((ext_vector_type(8)));
typedef _Float16 half4 __attribute__((ext_vector_type(4)));
typedef float f32x4 __attribute__((ext_vector_type(4)));

static __device__ __forceinline__ f32x4 mfma16(half8 a, half8 b, f32x4 c) {
    return __builtin_amdgcn_mfma_f32_16x16x32_f16(a, b, c, 0, 0, 0);
}

// async global->LDS, 16B per lane (GEMM staging only)
static __device__ __forceinline__ void gload16(const f16* g, f16* l) {
    __builtin_amdgcn_global_load_lds(
        (const __attribute__((address_space(1))) unsigned int*)g,
        (__attribute__((address_space(3))) unsigned int*)l, 16, 0, 0);
}

// ---------------- fused elementwise converts ----------------
__global__ void k_elem(const float* __restrict__ q_w, const float* __restrict__ k_w,
                       const float* __restrict__ v_w, const float* __restrict__ query,
                       const float* __restrict__ key, const float* __restrict__ value,
                       const float* __restrict__ owm, const float* __restrict__ owl,
                       const float* __restrict__ eps,
                       f16* qw16, f16* kw16, f16* vw16,
                       f16* xq16, f16* xk16, f16* xv16, f16* ow16)
{
    int y = blockIdx.y;
    size_t i = ((size_t)blockIdx.x * 256 + threadIdx.x) * 4;
    if (y < 3) {
        if (i >= (size_t)EE*EE) return;
        const float* s = (y==0) ? q_w : (y==1) ? k_w : v_w;
        f16* d = (y==0) ? qw16 : (y==1) ? kw16 : vw16;
        float4 v = *(const float4*)&s[i];
        half4 o = {(f16)v.x, (f16)v.y, (f16)v.z, (f16)v.w};
        *(half4*)&d[i] = o;
    } else if (y < 6) {
        const float* s = (y==3) ? query : (y==4) ? key : value;
        f16* d = (y==3) ? xq16 : (y==4) ? xk16 : xv16;
        float4 v = *(const float4*)&s[i];
        half4 o = {(f16)v.x, (f16)v.y, (f16)v.z, (f16)v.w};
        *(half4*)&d[i] = o;
    } else {
        if (i >= (size_t)EE*EE) return;
        float4 m = *(const float4*)&owm[i];
        float4 l = *(const float4*)&owl[i];
        float4 e = *(const float4*)&eps[i];
        half4 o = {(f16)(m.x + e.x * __expf(l.x)), (f16)(m.y + e.y * __expf(l.y)),
                   (f16)(m.z + e.z * __expf(l.z)), (f16)(m.w + e.w * __expf(l.w))};
        *(half4*)&ow16[i] = o;
    }
}

// ---------------- GEMM body: C[M,N] = (A[M,K] @ W[N,K]^T + bias) * scale ----------------
// 128x64 tile, BK=32.
// mode 0: f16 -> [b][h][s][d]            (attention-coalesced Q/K)
// mode 1: f16 -> [b][h][s/32][d][32]     (attention-coalesced V^T, k-tiled)
// mode 2: f32 row-major [m][col]
__device__ __forceinline__ void gemm_body(
    const f16* __restrict__ A, const f16* __restrict__ W,
    const float* __restrict__ bias, float scale, void* __restrict__ out, int mode)
{
    __shared__ f16 As[128*32];
    __shared__ f16 Bs[64*32];
    int t = threadIdx.x, lane = t & 63, w = t >> 6;
    int quad = lane >> 4, m16 = lane & 15;
    int wm = w >> 1, wn = w & 1;
    int gm0 = blockIdx.x * 128, gn0 = blockIdx.y * 64;
    int arow = lane >> 2, apch = lane & 3;
    f32x4 acc[4][2] = {};
    for (int kt = 0; kt < EE; kt += 32) {
        #pragma unroll
        for (int j = 0; j < 2; ++j) {
            int row = w*32 + j*16 + arow;
            int lch = apch ^ (row & 3);
            gload16(&A[(size_t)(gm0+row)*EE + kt + lch*8], &As[row*32 + apch*8]);
        }
        {
            int row = w*16 + arow;
            int lch = apch ^ (row & 3);
            gload16(&W[(size_t)(gn0+row)*EE + kt + lch*8], &Bs[row*32 + apch*8]);
        }
        __syncthreads();
        int cs = (quad ^ (m16 & 3)) * 8;
        half8 af[4], bf[2];
        #pragma unroll
        for (int i = 0; i < 4; ++i) af[i] = *(half8*)&As[(wm*64 + i*16 + m16)*32 + cs];
        #pragma unroll
        for (int j = 0; j < 2; ++j) bf[j] = *(half8*)&Bs[(wn*32 + j*16 + m16)*32 + cs];
        #pragma unroll
        for (int i = 0; i < 4; ++i)
            #pragma unroll
            for (int j = 0; j < 2; ++j)
                acc[i][j] = mfma16(af[i], bf[j], acc[i][j]);
        __syncthreads();
    }
    #pragma unroll
    for (int j = 0; j < 2; ++j) {
        int col = gn0 + wn*32 + j*16 + m16;
        int h = col >> 6, d = col & 63;
        float bb = bias ? bias[col] : 0.0f;
        #pragma unroll
        for (int i = 0; i < 4; ++i) {
            int r0 = gm0 + wm*64 + i*16 + quad*4;
            #pragma unroll
            for (int r = 0; r < 4; ++r) {
                float v = (acc[i][j][r] + bb) * scale;
                int m = r0 + r;
                int s = m >> 1, b = m & 1;
                if (mode == 2)
                    ((float*)out)[(size_t)m*EE + col] = v;
                else if (mode == 1)
                    ((f16*)out)[((((size_t)b*HH + h)*(SQ/32) + (s >> 5))*DD + d)*32 + (s & 31)] = (f16)v;
                else
                    ((f16*)out)[(((size_t)b*HH + h)*SQ + s)*DD + d] = (f16)v;
            }
        }
    }
}

__global__ __launch_bounds__(256) void k_gemm_qkv(
    const f16* xq, const f16* qw, const float* qb,
    const f16* xk, const f16* kw, const float* kb,
    const f16* xv, const f16* vw, const float* vb,
    f16* Q16, f16* K16, f16* Vt16)
{
    int z = blockIdx.z;
    const f16* A = (z==0) ? xq : (z==1) ? xk : xv;
    const f16* W = (z==0) ? qw : (z==1) ? kw : vw;
    const float* bi = (z==0) ? qb : (z==1) ? kb : vb;
    float sc = (z==0) ? 0.125f * LOG2E : 1.0f;   // fold log2e into Q
    void* o = (z==0) ? (void*)Q16 : (z==1) ? (void*)K16 : (void*)Vt16;
    gemm_body(A, W, bi, sc, o, (z==2) ? 1 : 0);
}

__global__ __launch_bounds__(256) void k_gemm_o(const f16* A, const f16* W, float* out)
{
    gemm_body(A, W, nullptr, 1.0f, out, 2);
}

// ---------------- phase 1: lse2[b,h,q] = log2(sum_k 2^s2) ----------------
// Q16/K16 are [b][h][s][d]: frag loads are dense contiguous spans per wave.
// Flat 1024-wg grid, XCD-swizzled: combo (h,b) c sits entirely on XCD c&7
// (hardware round-robins blockIdx%8 across the 8 XCDs), so each XCD's hot
// K slices (4 combos x 256KB = 1MB) are L2-resident instead of L3-served.
__global__ __launch_bounds__(256, 4) void k_attn_l(
    const f16* __restrict__ Q16, const f16* __restrict__ K16, float* __restrict__ lse2)
{
    __shared__ float red[4][64];
    const int t = threadIdx.x, lane = t & 63, w = t >> 6;
    const int quad = lane >> 4, m16 = lane & 15;
    const int bid = blockIdx.x;
    const int xcd = bid & 7, r = bid >> 3;       // r in [0,128)
    const int c = ((r & 3) << 3) + xcd;          // (h,b) combo, c&7 == xcd
    const int q0 = (r >> 2) * 64;                // q-tile in [0,32)*64
    const int h = c >> 1, b = c & 1;
    const f16* Qh = Q16 + ((size_t)b*HH + h)*SQ*DD;
    const f16* Kh = K16 + ((size_t)b*HH + h)*SQ*DD;

    half8 bq[4][2];
    #pragma unroll
    for (int nt = 0; nt < 4; ++nt)
        #pragma unroll
        for (int dk = 0; dk < 2; ++dk)
            bq[nt][dk] = *(const half8*)&Qh[(q0 + nt*16 + m16)*DD + dk*32 + quad*8];

    float lsum[4] = {};
    for (int kt = 0; kt < 16; ++kt) {
        half8 ak[2][2];
        #pragma unroll
        for (int mt = 0; mt < 2; ++mt)
            #pragma unroll
            for (int dk = 0; dk < 2; ++dk)
                ak[mt][dk] = *(const half8*)&Kh[(kt*128 + w*32 + mt*16 + m16)*DD + dk*32 + quad*8];
        #pragma unroll
        for (int mt = 0; mt < 2; ++mt)
            #pragma unroll
            for (int nt = 0; nt < 4; ++nt) {
                f32x4 s = {};
                s = mfma16(ak[mt][0], bq[nt][0], s);   // S^T: rows k, cols q
                s = mfma16(ak[mt][1], bq[nt][1], s);
                lsum[nt] += __builtin_amdgcn_exp2f(s[0]) + __builtin_amdgcn_exp2f(s[1])
                          + __builtin_amdgcn_exp2f(s[2]) + __builtin_amdgcn_exp2f(s[3]);
            }
    }
    #pragma unroll
    for (int nt = 0; nt < 4; ++nt) {
        float v = lsum[nt];
        v += __shfl_xor(v, 16, 64);
        v += __shfl_xor(v, 32, 64);
        lsum[nt] = v;
    }
    if (quad == 0)
        #pragma unroll
        for (int nt = 0; nt < 4; ++nt) red[w][nt*16 + m16] = lsum[nt];
    __syncthreads();
    if (t < 64) {
        float v = red[0][t] + red[1][t] + red[2][t] + red[3][t];
        lse2[((size_t)b*HH + h)*SQ + q0 + t] = __log2f(v);
    }
}

// ---------------- phase 2: probs, avg_attn (regs), ctx partials ----------------
// Flat 512-wg grid, XCD-swizzled: (sl,b) group g = bid&7 sits entirely on XCD g,
// so the group's K+V slice (2MB) is L2-resident for all 64 q-tile wgs re-reading
// it (was: every XCD touching all 16MB -> L2 thrash -> L3-BW-bound at ~8TB/s).
// K/V frags direct from global, software-pipelined; lgkm-only barrier (T4).
__global__ __launch_bounds__(256, 2) void k_attn_main(
    const f16* __restrict__ Q16, const f16* __restrict__ K16, const f16* __restrict__ Vt16,
    const float* __restrict__ lse2, float* __restrict__ ctxp, float* __restrict__ avg_out)
{
    __shared__ f16 ps[2][32][136];
    __shared__ float csh[HH][32];
    const int t = threadIdx.x, lane = t & 63, w = t >> 6;
    const int quad = lane >> 4, m16 = lane & 15;
    const int bid = blockIdx.x;
    const int g = bid & 7;                 // (sl,b) group == XCD
    const int q0 = (bid >> 3) * 32;        // q-tile in [0,64)*32
    const int sl = g >> 1, b = g & 1;
    const int ks0 = sl * KSLICE;

    for (int i = t; i < HH*32; i += 256) {
        int hh = i >> 5, qq = i & 31;
        csh[hh][qq] = lse2[((size_t)b*HH + hh)*SQ + q0 + qq];
    }
    __syncthreads();

    float avg_r[KT_IN][16] = {};   // lane-exclusive (q,k) slots, accumulated over h

    for (int hp = 0; hp < 8; ++hp) {
        f32x4 acc[2][2] = {};
        for (int hh2 = 0; hh2 < 2; ++hh2) {
            const int h = hp*2 + hh2;
            const f16* Qh = Q16 + ((size_t)b*HH + h)*SQ*DD;
            const f16* Kh = K16 + ((size_t)b*HH + h)*SQ*DD;
            const f16* Vh = Vt16 + ((size_t)b*HH + h)*(SQ/32)*DD*32;
            half8 bq[2][2];
            #pragma unroll
            for (int nt = 0; nt < 2; ++nt)
                #pragma unroll
                for (int dk = 0; dk < 2; ++dk)
                    bq[nt][dk] = *(const half8*)&Qh[(q0 + nt*16 + m16)*DD + dk*32 + quad*8];
            const float c01[2] = { csh[h][m16], csh[h][16 + m16] };

            half8 ak[2][2][2], bv[2][4];
            #pragma unroll
            for (int mt = 0; mt < 2; ++mt)
                #pragma unroll
                for (int dk = 0; dk < 2; ++dk)
                    ak[0][mt][dk] = *(const half8*)&Kh[(ks0 + w*32 + mt*16 + m16)*DD + dk*32 + quad*8];
            #pragma unroll
            for (int ks = 0; ks < 4; ++ks)
                bv[0][ks] = *(const half8*)&Vh[(((ks0 + ks*32) >> 5)*DD + w*16 + m16)*32 + quad*8];

            #pragma unroll
            for (int kt = 0; kt < KT_IN; ++kt) {
                const int cur = kt & 1, nxt = cur ^ 1;
                if (kt + 1 < KT_IN) {   // prefetch next tile's fragments
                    #pragma unroll
                    for (int mt = 0; mt < 2; ++mt)
                        #pragma unroll
                        for (int dk = 0; dk < 2; ++dk)
                            ak[nxt][mt][dk] = *(const half8*)&Kh[(ks0 + (kt+1)*128 + w*32 + mt*16 + m16)*DD + dk*32 + quad*8];
                    #pragma unroll
                    for (int ks = 0; ks < 4; ++ks)
                        bv[nxt][ks] = *(const half8*)&Vh[(((ks0 + (kt+1)*128 + ks*32) >> 5)*DD + w*16 + m16)*32 + quad*8];
                }
                // S^T = K·Q^T: lane holds 4 consecutive k (rows), fixed q (col)
                #pragma unroll
                for (int mt = 0; mt < 2; ++mt)
                    #pragma unroll
                    for (int nt = 0; nt < 2; ++nt) {
                        f32x4 s = {};
                        s = mfma16(ak[cur][mt][0], bq[nt][0], s);
                        s = mfma16(ak[cur][mt][1], bq[nt][1], s);
                        half4 ph;
                        #pragma unroll
                        for (int r = 0; r < 4; ++r) {
                            float p = __builtin_amdgcn_exp2f(s[r] - c01[nt]);
                            avg_r[kt][mt*8 + nt*4 + r] += p;
                            ph[r] = (f16)p;
                        }
                        *(half4*)&ps[cur][nt*16 + m16][w*32 + mt*16 + quad*4] = ph;
                    }
                // ps[cur] exchange barrier: order LDS only (lgkmcnt(0)), keep global
                // prefetches in flight. sched_barrier(0) pins code motion (rule #18).
                __builtin_amdgcn_sched_barrier(0);
                __builtin_amdgcn_s_waitcnt(0xC07F);   // lgkmcnt(0), vmcnt/expcnt = max
                __builtin_amdgcn_s_barrier();
                __builtin_amdgcn_sched_barrier(0);
                // PV: ctx[32q x 64d] += P @ V; wave w owns d = w*16..+15
                #pragma unroll
                for (int qt = 0; qt < 2; ++qt) {
                    f32x4 c4 = acc[hh2][qt];
                    #pragma unroll
                    for (int ks = 0; ks < 4; ++ks) {
                        half8 ap = *(half8*)&ps[cur][qt*16 + m16][ks*32 + quad*8];
                        c4 = mfma16(ap, bv[cur][ks], c4);
                    }
                    acc[hh2][qt] = c4;
                }
            }
        }
        // flush 2 heads of ctx partials (fp32)
        #pragma unroll
        for (int hh2 = 0; hh2 < 2; ++hh2)
            #pragma unroll
            for (int qt = 0; qt < 2; ++qt)
                #pragma unroll
                for (int r = 0; r < 4; ++r) {
                    int q = q0 + qt*16 + quad*4 + r;
                    ctxp[(size_t)sl*MM*EE + ((size_t)q*BB + b)*EE + (hp*2 + hh2)*DD + w*16 + m16] = acc[hh2][qt][r];
                }
    }
    // write owned avg tile (float4 stores)
    #pragma unroll
    for (int kt = 0; kt < KT_IN; ++kt)
        #pragma unroll
        for (int mt = 0; mt < 2; ++mt)
            #pragma unroll
            for (int nt = 0; nt < 2; ++nt) {
                int q = q0 + nt*16 + m16;
                int k = ks0 + kt*128 + w*32 + mt*16 + quad*4;
                float4 v = { avg_r[kt][mt*8+nt*4+0]*(1.0f/HH), avg_r[kt][mt*8+nt*4+1]*(1.0f/HH),
                             avg_r[kt][mt*8+nt*4+2]*(1.0f/HH), avg_r[kt][mt*8+nt*4+3]*(1.0f/HH) };
                *(float4*)&avg_out[((size_t)b*SQ + q)*SQ + k] = v;
            }
}

// ---------------- ctx partial reduction: fp32 x NSLICE -> f16 ----------------
__global__ void k_ctx_red(const float* __restrict__ ctxp, f16* __restrict__ ctx16) {
    size_t i = ((size_t)blockIdx.x * 256 + threadIdx.x) * 4;
    float4 s = *(const float4*)&ctxp[i];
    #pragma unroll
    for (int sl = 1; sl < NSLICE; ++sl) {
        float4 v = *(const float4*)&ctxp[(size_t)sl*MM*EE + i];
        s.x += v.x; s.y += v.y; s.z += v.z; s.w += v.w;
    }
    half4 o = {(f16)s.x, (f16)s.y, (f16)s.z, (f16)s.w};
    *(half4*)&ctx16[i] = o;
}

// ---------------- launch ----------------
extern "C" void kernel_launch(void* const* d_in, const int* in_sizes, int n_in,
                              void* d_out, int out_size, void* d_ws, size_t ws_size,
                              hipStream_t stream) {
    const float* query    = (const float*)d_in[0];
    const float* key      = (const float*)d_in[1];
    const float* value    = (const float*)d_in[2];
    const float* q_w      = (const float*)d_in[3];
    const float* q_b      = (const float*)d_in[4];
    const float* k_w      = (const float*)d_in[5];
    const float* k_b      = (const float*)d_in[6];
    const float* v_w      = (const float*)d_in[7];
    const float* v_b      = (const float*)d_in[8];
    const float* o_w_mean = (const float*)d_in[9];
    const float* o_w_lgstd= (const float*)d_in[10];
    const float* eps      = (const float*)d_in[11];
    float* out = (float*)d_out;                  // [S,B,E] fp32
    float* avg = out + (size_t)MM * EE;          // [B,S,S] fp32

    const size_t EWN = (size_t)EE*EE;   // 1M
    const size_t XWN = (size_t)MM*EE;   // 4M
    f16* qw16  = (f16*)d_ws;
    f16* kw16  = qw16 + EWN;
    f16* vw16  = kw16 + EWN;
    f16* ow16  = vw16 + EWN;
    f16* Q16   = ow16 + EWN;
    f16* K16   = Q16  + XWN;
    f16* Vt16  = K16  + XWN;
    f16* ctx16 = Vt16 + XWN;
    float* lse2 = (float*)(ctx16 + XWN);             // B*H*S fp32
    f16* xq16  = (f16*)(lse2 + (size_t)BB*HH*SQ);
    f16* xk16  = xq16 + XWN;
    f16* xv16  = xk16 + XWN;
    // ctxp aliases xq/xk/xv (dead after projections) and extends beyond: NSLICE*16MB
    float* ctxp = (float*)xq16;

    k_elem<<<dim3(XWN/1024, 7), 256, 0, stream>>>(q_w, k_w, v_w, query, key, value,
        o_w_mean, o_w_lgstd, eps, qw16, kw16, vw16, xq16, xk16, xv16, ow16);

    k_gemm_qkv<<<dim3(MM/128, EE/64, 3), 256, 0, stream>>>(
        xq16, qw16, q_b, xk16, kw16, k_b, xv16, vw16, v_b, Q16, K16, Vt16);

    k_attn_l   <<<dim3(SQ/64 * HH * BB), 256, 0, stream>>>(Q16, K16, lse2);
    k_attn_main<<<dim3(SQ/32 * NSLICE * BB), 256, 0, stream>>>(Q16, K16, Vt16, lse2, ctxp, avg);
    k_ctx_red  <<<XWN/1024, 256, 0, stream>>>(ctxp, ctx16);

    k_gemm_o<<<dim3(MM/128, EE/64), 256, 0, stream>>>(ctx16, ow16, out);
}